// Round 7
// baseline (299.471 us; speedup 1.0000x reference)
//
#include <hip/hip_runtime.h>
#include <hip/hip_bf16.h>

// AttentionBlock: GroupNorm -> QKV proj -> channel-attention -> out proj -> residual
// B=8, T=1024, C=512, H=4, GROUPS=32, logits scale 1/32.
//
// bf16 MFMA 16x16x32, fp32 accum. 128x128 BK=64 mainloop for gemm1/3;
// 128x64 BK=64 for gemm4 (grid 512 = 2 blocks/CU). attn_kernel fuses
// QK^T/32 + softmax with 32-row strips (grid 512 = 2 blocks/CU).
// Staging: global_load_lds width=16 into XOR-swizzled stride-32 LDS (0 conflicts).

typedef __bf16 bf16x8 __attribute__((ext_vector_type(8)));
typedef float f32x4 __attribute__((ext_vector_type(4)));

__device__ __forceinline__ unsigned short f2bf(float f) {
  union { float f; unsigned u; } x; x.f = f;
  unsigned r = x.u + 0x7fffu + ((x.u >> 16) & 1u);   // RNE
  return (unsigned short)(r >> 16);
}

__device__ __forceinline__ void gload_lds16(const unsigned short* g, unsigned short* l) {
  __builtin_amdgcn_global_load_lds(
      (const __attribute__((address_space(1))) void*)g,
      (__attribute__((address_space(3))) void*)l, 16, 0, 0);
}

// ---------------------------------------------------------------------------
// 128x128 main loop, BK=64: C = A * BT^T; 4 waves each 64x64 (acc 4x4).
// As/Bs each hold two BK=32 sub-tiles at +0/+4096 (32 KB total).
// ---------------------------------------------------------------------------
__device__ __forceinline__ void gemm_mainloop(
    const unsigned short* __restrict__ A, const unsigned short* __restrict__ BT,
    int K, int row0, int col0,
    unsigned short* As, unsigned short* Bs, f32x4 acc[4][4]) {
  const int tid = threadIdx.x;
  const int lane = tid & 63, wave = tid >> 6;
  const int wm = (wave >> 1) << 6, wn = (wave & 1) << 6;
  const int rl = lane & 15;
  const int swz = (((lane >> 4) ^ ((rl >> 1) & 3)) << 3);
  const int srow = tid >> 2;
  const int sg = (((tid & 3) ^ ((tid >> 3) & 3)) << 3);
  const unsigned short* a0 = A + (size_t)(row0 + srow) * K + sg;
  const unsigned short* a1 = A + (size_t)(row0 + 64 + srow) * K + sg;
  const unsigned short* b0 = BT + (size_t)(col0 + srow) * K + sg;
  const unsigned short* b1 = BT + (size_t)(col0 + 64 + srow) * K + sg;
  unsigned short* lA0 = As + tid * 8;
  unsigned short* lA1 = As + 2048 + tid * 8;
  unsigned short* lB0 = Bs + tid * 8;
  unsigned short* lB1 = Bs + 2048 + tid * 8;
#pragma unroll
  for (int mi = 0; mi < 4; mi++)
#pragma unroll
    for (int ni = 0; ni < 4; ni++)
      acc[mi][ni] = (f32x4){0.f, 0.f, 0.f, 0.f};

  for (int k0 = 0; k0 < K; k0 += 64) {
    __syncthreads();
    gload_lds16(a0 + k0, lA0);
    gload_lds16(a1 + k0, lA1);
    gload_lds16(b0 + k0, lB0);
    gload_lds16(b1 + k0, lB1);
    gload_lds16(a0 + k0 + 32, lA0 + 4096);
    gload_lds16(a1 + k0 + 32, lA1 + 4096);
    gload_lds16(b0 + k0 + 32, lB0 + 4096);
    gload_lds16(b1 + k0 + 32, lB1 + 4096);
    __syncthreads();
#pragma unroll
    for (int h = 0; h < 2; h++) {
      const unsigned short* Ah = As + h * 4096;
      const unsigned short* Bh = Bs + h * 4096;
      bf16x8 af[4], bfr[4];
#pragma unroll
      for (int mi = 0; mi < 4; mi++)
        af[mi] = *(const bf16x8*)(Ah + (wm + mi * 16 + rl) * 32 + swz);
#pragma unroll
      for (int ni = 0; ni < 4; ni++)
        bfr[ni] = *(const bf16x8*)(Bh + (wn + ni * 16 + rl) * 32 + swz);
#pragma unroll
      for (int mi = 0; mi < 4; mi++)
#pragma unroll
        for (int ni = 0; ni < 4; ni++)
          acc[mi][ni] = __builtin_amdgcn_mfma_f32_16x16x32_bf16(
              af[mi], bfr[ni], acc[mi][ni], 0, 0, 0);
    }
  }
}

// ---------------------------------------------------------------------------
// 128x64 main loop, BK=64: 4 waves each 64x32 (acc 4x2).
// As: 128 rows (2 halves at +0/+4096, 8192 elems). Bs: 64 rows (halves at
// +0/+2048, 4096 elems). 24 KB total.
// ---------------------------------------------------------------------------
__device__ __forceinline__ void gemm_mainloop_12864(
    const unsigned short* __restrict__ A, const unsigned short* __restrict__ BT,
    int K, int row0, int col0,
    unsigned short* As, unsigned short* Bs, f32x4 acc[4][2]) {
  const int tid = threadIdx.x;
  const int lane = tid & 63, wave = tid >> 6;
  const int wm = (wave >> 1) << 6, wn = (wave & 1) << 5;
  const int rl = lane & 15;
  const int swz = (((lane >> 4) ^ ((rl >> 1) & 3)) << 3);
  const int srow = tid >> 2;
  const int sg = (((tid & 3) ^ ((tid >> 3) & 3)) << 3);
  const unsigned short* a0 = A + (size_t)(row0 + srow) * K + sg;
  const unsigned short* a1 = A + (size_t)(row0 + 64 + srow) * K + sg;
  const unsigned short* b0 = BT + (size_t)(col0 + srow) * K + sg;
  unsigned short* lA0 = As + tid * 8;
  unsigned short* lA1 = As + 2048 + tid * 8;
  unsigned short* lB0 = Bs + tid * 8;
#pragma unroll
  for (int mi = 0; mi < 4; mi++)
#pragma unroll
    for (int ni = 0; ni < 2; ni++)
      acc[mi][ni] = (f32x4){0.f, 0.f, 0.f, 0.f};

  for (int k0 = 0; k0 < K; k0 += 64) {
    __syncthreads();
    gload_lds16(a0 + k0, lA0);
    gload_lds16(a1 + k0, lA1);
    gload_lds16(b0 + k0, lB0);
    gload_lds16(a0 + k0 + 32, lA0 + 4096);
    gload_lds16(a1 + k0 + 32, lA1 + 4096);
    gload_lds16(b0 + k0 + 32, lB0 + 2048);
    __syncthreads();
#pragma unroll
    for (int h = 0; h < 2; h++) {
      const unsigned short* Ah = As + h * 4096;
      const unsigned short* Bh = Bs + h * 2048;
      bf16x8 af[4], bfr[2];
#pragma unroll
      for (int mi = 0; mi < 4; mi++)
        af[mi] = *(const bf16x8*)(Ah + (wm + mi * 16 + rl) * 32 + swz);
#pragma unroll
      for (int ni = 0; ni < 2; ni++)
        bfr[ni] = *(const bf16x8*)(Bh + (wn + ni * 16 + rl) * 32 + swz);
#pragma unroll
      for (int mi = 0; mi < 4; mi++)
#pragma unroll
        for (int ni = 0; ni < 2; ni++)
          acc[mi][ni] = __builtin_amdgcn_mfma_f32_16x16x32_bf16(
              af[mi], bfr[ni], acc[mi][ni], 0, 0, 0);
    }
  }
}

// ---------------------------------------------------------------------------
// Transposed tile store (128x128 accs): dst[(n0+n)*ldd + m_off+m] via LDS.
// ---------------------------------------------------------------------------
__device__ __forceinline__ void epilogue_transpose_store(
    f32x4 acc[4][4], unsigned short* ebuf, unsigned short* dst,
    size_t n0, int ldd, int m_off,
    const float* bias, int bias_base, int bias_stride, int bias_c0) {
  const int tid = threadIdx.x, lane = tid & 63, wave = tid >> 6;
  const int wm = (wave >> 1) << 6;
#pragma unroll
  for (int p = 0; p < 2; p++) {
    __syncthreads();
    if ((wave & 1) == p) {
#pragma unroll
      for (int ni = 0; ni < 4; ni++) {
        const int nl = ni * 16 + (lane & 15);
        const float bq =
            bias ? bias[bias_base + (bias_c0 + p * 64 + nl) * bias_stride] : 0.f;
#pragma unroll
        for (int mi = 0; mi < 4; mi++) {
          const int m = wm + mi * 16 + ((lane >> 4) << 2);
          unsigned short t4[4];
#pragma unroll
          for (int reg = 0; reg < 4; reg++) t4[reg] = f2bf(acc[mi][ni][reg] + bq);
          *(uint2*)(ebuf + nl * 132 + m) = *(const uint2*)t4;
        }
      }
    }
    __syncthreads();
#pragma unroll
    for (int r = 0; r < 2; r++) {
      const int nl = (tid >> 3) + 32 * r;
      const int m = (tid & 7) * 16;
      uint4 v0 = *(const uint4*)(ebuf + nl * 132 + m);
      uint4 v1 = *(const uint4*)(ebuf + nl * 132 + m + 8);
      unsigned short* d = dst + (n0 + p * 64 + nl) * (size_t)ldd + m_off + m;
      *(uint4*)d = v0;
      *(uint4*)(d + 8) = v1;
    }
  }
}

// ---------------------------------------------------------------------------
// GroupNorm: one block per (b, g).
// ---------------------------------------------------------------------------
__global__ __launch_bounds__(256) void groupnorm_kernel(
    const float* __restrict__ x, const float* __restrict__ scale,
    const float* __restrict__ bias, unsigned short* __restrict__ h) {
  const int b = blockIdx.x >> 5, g = blockIdx.x & 31;
  const float* xb = x + ((size_t)b * 1024) * 512 + g * 16;
  __shared__ float red[8];
  __shared__ float stats[2];
  float s = 0.f, ss = 0.f;
  for (int t = threadIdx.x; t < 1024; t += 256) {
    const float4* p = (const float4*)(xb + (size_t)t * 512);
#pragma unroll
    for (int j = 0; j < 4; j++) {
      float4 u = p[j];
      s += u.x + u.y + u.z + u.w;
      ss += u.x * u.x + u.y * u.y + u.z * u.z + u.w * u.w;
    }
  }
  const int lane = threadIdx.x & 63, wave = threadIdx.x >> 6;
  for (int o = 32; o; o >>= 1) {
    s += __shfl_down(s, o, 64);
    ss += __shfl_down(ss, o, 64);
  }
  if (lane == 0) { red[wave] = s; red[4 + wave] = ss; }
  __syncthreads();
  if (threadIdx.x == 0) {
    float ts = red[0] + red[1] + red[2] + red[3];
    float tss = red[4] + red[5] + red[6] + red[7];
    float mean = ts * (1.f / 16384.f);
    float var = tss * (1.f / 16384.f) - mean * mean;
    stats[0] = mean;
    stats[1] = rsqrtf(var + 1e-5f);
  }
  __syncthreads();
  const float mean = stats[0], inv = stats[1];
  float sc[16], bi[16];
#pragma unroll
  for (int j = 0; j < 16; j++) {
    sc[j] = scale[g * 16 + j] * inv;
    bi[j] = bias[g * 16 + j];
  }
  for (int t = threadIdx.x; t < 1024; t += 256) {
    const float4* p = (const float4*)(xb + (size_t)t * 512);
    unsigned short o16[16];
#pragma unroll
    for (int j = 0; j < 4; j++) {
      float4 u = p[j];
      o16[j * 4 + 0] = f2bf((u.x - mean) * sc[j * 4 + 0] + bi[j * 4 + 0]);
      o16[j * 4 + 1] = f2bf((u.y - mean) * sc[j * 4 + 1] + bi[j * 4 + 1]);
      o16[j * 4 + 2] = f2bf((u.z - mean) * sc[j * 4 + 2] + bi[j * 4 + 2]);
      o16[j * 4 + 3] = f2bf((u.w - mean) * sc[j * 4 + 3] + bi[j * 4 + 3]);
    }
    uint4* dst = (uint4*)(h + ((size_t)(b * 1024 + t)) * 512 + g * 16);
    dst[0] = *(uint4*)(o16);
    dst[1] = *(uint4*)(o16 + 8);
  }
}

// ---------------------------------------------------------------------------
// Tiled weight transpose fp32 (R,N) -> bf16 (N,R); mode 1 = qkv column reorder.
// ---------------------------------------------------------------------------
__global__ __launch_bounds__(256) void transpose_w_kernel(
    const float* __restrict__ w, unsigned short* __restrict__ wT,
    int R, int N, int mode) {
  __shared__ unsigned short buf[64 * 72];
  const int n0 = blockIdx.x * 64, r0 = blockIdx.y * 64;
  const int t = threadIdx.x;
  {
    const int rl = t >> 2, nc = (t & 3) * 16;
    const float* src = w + (size_t)(r0 + rl) * N + n0 + nc;
#pragma unroll
    for (int j = 0; j < 16; j++) buf[(nc + j) * 72 + rl] = f2bf(src[j]);
  }
  __syncthreads();
  {
    const int nl = t >> 2, rc = (t & 3) * 16;
    const int n = n0 + nl;
    int p;
    if (mode == 1) {
      const int hh = n / 1536, rem = n - hh * 1536;
      const int c = rem / 3, s = rem - c * 3;
      p = s * 2048 + hh * 512 + c;
    } else {
      p = n;
    }
    unsigned short tmp[16];
#pragma unroll
    for (int j = 0; j < 16; j++) tmp[j] = buf[nl * 72 + rc + j];
    uint4* d = (uint4*)(wT + (size_t)p * R + r0 + rc);
    d[0] = *(const uint4*)tmp;
    d[1] = *(const uint4*)(tmp + 8);
  }
}

// ---------------------------------------------------------------------------
// GEMM1: qkv = h(8192,512) x wqkvT(6144,512)^T (rows (s,h,c)-ordered).
// ---------------------------------------------------------------------------
__global__ __launch_bounds__(256, 3) void gemm1_kernel(
    const unsigned short* __restrict__ h, const unsigned short* __restrict__ wqkvT,
    const float* __restrict__ b_qkv, unsigned short* __restrict__ q,
    unsigned short* __restrict__ k, unsigned short* __restrict__ vT) {
  __shared__ unsigned short smem[16384];
  unsigned short* As = smem;
  unsigned short* Bs = smem + 8192;
  const int row0 = blockIdx.y << 7, col0 = blockIdx.x << 7;
  f32x4 acc[4][4];
  gemm_mainloop(h, wqkvT, 512, row0, col0, As, Bs, acc);

  const int s = col0 >> 11, hh = (col0 >> 9) & 3, c0 = col0 & 511;
  const int b = row0 >> 10, tt0 = row0 & 1023;
  const int bh = b * 4 + hh;
  if (s == 2) {
    const int lane = threadIdx.x & 63, wave = threadIdx.x >> 6;
    const int wm = (wave >> 1) << 6, wn = (wave & 1) << 6;
#pragma unroll
    for (int mi = 0; mi < 4; mi++) {
      const int rbase = tt0 + wm + mi * 16 + ((lane >> 4) << 2);
#pragma unroll
      for (int ni = 0; ni < 4; ni++) {
        const int cc = c0 + wn + ni * 16 + (lane & 15);
        const float bq = b_qkv[hh * 1536 + cc * 3 + 2];
#pragma unroll
        for (int reg = 0; reg < 4; reg++)
          vT[((size_t)(bh * 1024 + rbase + reg)) * 512 + cc] =
              f2bf(acc[mi][ni][reg] + bq);
      }
    }
  } else {
    epilogue_transpose_store(acc, smem, (s == 0) ? q : k,
                             (size_t)bh * 512 + c0, 1024, tt0,
                             b_qkv, hh * 1536 + s, 3, c0);
  }
}

// ---------------------------------------------------------------------------
// Fused attention scores: per block, S[32 c-rows x 512 d-cols] = Q K^T / 32,
// softmax over d, write bf16 attn.  z = blockIdx.x >> 4, strip = blockIdx.x & 15.
// 4 waves; wave w owns cols [w*128, w*128+128): acc[2][8].
// Grid 512 = 2 blocks/CU (launch_bounds(256,2)); ~35 KB LDS.
// ---------------------------------------------------------------------------
__global__ __launch_bounds__(256, 2) void attn_kernel(
    const unsigned short* __restrict__ q, const unsigned short* __restrict__ k,
    unsigned short* __restrict__ attn) {
  __shared__ unsigned short As[32 * 32];
  __shared__ unsigned short Bs[512 * 32];
  __shared__ float red_m[4][32];
  __shared__ float red_s[4][32];
  const int z = blockIdx.x >> 4, strip = blockIdx.x & 15;
  const unsigned short* Q = q + (size_t)z * 512 * 1024 + (size_t)strip * 32 * 1024;
  const unsigned short* K = k + (size_t)z * 512 * 1024;
  unsigned short* P = attn + (size_t)z * 512 * 512 + (size_t)strip * 32 * 512;

  const int tid = threadIdx.x, lane = tid & 63, wave = tid >> 6;
  const int rl = lane & 15, qd = lane >> 4;
  const int swz = ((qd ^ ((rl >> 1) & 3)) << 3);
  const int srow = tid >> 2;
  const int sg = (((tid & 3) ^ ((tid >> 3) & 3)) << 3);
  const unsigned short* qa = Q + (size_t)srow * 1024 + sg;
  const unsigned short* kb = K + (size_t)srow * 1024 + sg;
  unsigned short* lA = As + tid * 8;
  unsigned short* lB = Bs + tid * 8;

  f32x4 acc[2][8];
#pragma unroll
  for (int mi = 0; mi < 2; mi++)
#pragma unroll
    for (int ni = 0; ni < 8; ni++)
      acc[mi][ni] = (f32x4){0.f, 0.f, 0.f, 0.f};

  for (int k0 = 0; k0 < 1024; k0 += 32) {
    __syncthreads();
    if (tid < 128) gload_lds16(qa + k0, lA);   // 32 rows x 32: waves 0-1 only
#pragma unroll
    for (int c = 0; c < 8; c++)
      gload_lds16(kb + (size_t)c * 64 * 1024 + k0, lB + c * 2048);
    __syncthreads();
    bf16x8 af[2], bfr[8];
#pragma unroll
    for (int mi = 0; mi < 2; mi++)
      af[mi] = *(const bf16x8*)(As + (mi * 16 + rl) * 32 + swz);
#pragma unroll
    for (int ni = 0; ni < 8; ni++) {
      const int chunk = wave * 2 + (ni >> 2);
      bfr[ni] = *(const bf16x8*)(Bs + chunk * 2048 + ((ni & 3) * 16 + rl) * 32 + swz);
    }
#pragma unroll
    for (int mi = 0; mi < 2; mi++)
#pragma unroll
      for (int ni = 0; ni < 8; ni++)
        acc[mi][ni] = __builtin_amdgcn_mfma_f32_16x16x32_bf16(
            af[mi], bfr[ni], acc[mi][ni], 0, 0, 0);
  }

  // ---- softmax over the 512 cols (raw logits; scale folded into exp) ----
  float pm[2][4];
#pragma unroll
  for (int mi = 0; mi < 2; mi++)
#pragma unroll
    for (int reg = 0; reg < 4; reg++) {
      float m = acc[mi][0][reg];
#pragma unroll
      for (int ni = 1; ni < 8; ni++) m = fmaxf(m, acc[mi][ni][reg]);
      pm[mi][reg] = m;
    }
#pragma unroll
  for (int o = 1; o < 16; o <<= 1)
#pragma unroll
    for (int mi = 0; mi < 2; mi++)
#pragma unroll
      for (int reg = 0; reg < 4; reg++)
        pm[mi][reg] = fmaxf(pm[mi][reg], __shfl_xor(pm[mi][reg], o, 64));
  if (rl == 0)
#pragma unroll
    for (int mi = 0; mi < 2; mi++)
#pragma unroll
      for (int reg = 0; reg < 4; reg++)
        red_m[wave][mi * 16 + qd * 4 + reg] = pm[mi][reg];
  __syncthreads();
  float mf[2][4], ps[2][4];
#pragma unroll
  for (int mi = 0; mi < 2; mi++)
#pragma unroll
    for (int reg = 0; reg < 4; reg++) {
      const int row = mi * 16 + qd * 4 + reg;
      mf[mi][reg] = fmaxf(fmaxf(red_m[0][row], red_m[1][row]),
                          fmaxf(red_m[2][row], red_m[3][row]));
      ps[mi][reg] = 0.f;
    }
#pragma unroll
  for (int mi = 0; mi < 2; mi++)
#pragma unroll
    for (int ni = 0; ni < 8; ni++)
#pragma unroll
      for (int reg = 0; reg < 4; reg++) {
        const float e = __expf((acc[mi][ni][reg] - mf[mi][reg]) * 0.03125f);
        acc[mi][ni][reg] = e;
        ps[mi][reg] += e;
      }
#pragma unroll
  for (int o = 1; o < 16; o <<= 1)
#pragma unroll
    for (int mi = 0; mi < 2; mi++)
#pragma unroll
      for (int reg = 0; reg < 4; reg++)
        ps[mi][reg] += __shfl_xor(ps[mi][reg], o, 64);
  if (rl == 0)
#pragma unroll
    for (int mi = 0; mi < 2; mi++)
#pragma unroll
      for (int reg = 0; reg < 4; reg++)
        red_s[wave][mi * 16 + qd * 4 + reg] = ps[mi][reg];
  __syncthreads();
#pragma unroll
  for (int mi = 0; mi < 2; mi++)
#pragma unroll
    for (int reg = 0; reg < 4; reg++) {
      const int row = mi * 16 + qd * 4 + reg;
      const float inv = 1.f / (red_s[0][row] + red_s[1][row] +
                               red_s[2][row] + red_s[3][row]);
      unsigned short* pr = P + (size_t)row * 512 + wave * 128 + rl;
#pragma unroll
      for (int ni = 0; ni < 8; ni++)
        pr[ni * 16] = f2bf(acc[mi][ni][reg] * inv);
    }
}

// ---------------------------------------------------------------------------
// GEMM3: av[z](c,t) = attn[z](512,512) x vT[z](1024,512)^T -> hv (b,t,h*512+c).
// ---------------------------------------------------------------------------
__global__ __launch_bounds__(256, 3) void gemm3_kernel(
    const unsigned short* __restrict__ attn, const unsigned short* __restrict__ vT,
    unsigned short* __restrict__ hv) {
  __shared__ unsigned short smem[16384];
  unsigned short* As = smem;
  unsigned short* Bs = smem + 8192;
  const int z = blockIdx.z;
  const int bb = z >> 2, hh = z & 3;
  const unsigned short* A = attn + (size_t)z * 512 * 512;
  const unsigned short* BT = vT + (size_t)z * 1024 * 512;
  const int row0 = blockIdx.y << 7, col0 = blockIdx.x << 7;
  f32x4 acc[4][4];
  gemm_mainloop(A, BT, 512, row0, col0, As, Bs, acc);
  epilogue_transpose_store(acc, smem, hv,
                           (size_t)bb * 1024 + col0, 2048, hh * 512 + row0,
                           nullptr, 0, 0, 0);
}

// ---------------------------------------------------------------------------
// GEMM4: out = hv(8192,2048) x woutT(512,2048)^T + b_out + x, fp32.
// 128x64 tiles, BK=64; grid (8,64) = 512 blocks = 2 blocks/CU.
// ---------------------------------------------------------------------------
__global__ __launch_bounds__(256, 2) void gemm4_kernel(
    const unsigned short* __restrict__ hv, const unsigned short* __restrict__ woutT,
    const float* __restrict__ b_out, const float* __restrict__ x,
    float* __restrict__ out) {
  __shared__ unsigned short smem[12288];
  unsigned short* As = smem;
  unsigned short* Bs = smem + 8192;
  const int row0 = blockIdx.y << 7, col0 = blockIdx.x << 6;
  f32x4 acc[4][2];
  gemm_mainloop_12864(hv, woutT, 2048, row0, col0, As, Bs, acc);
  const int lane = threadIdx.x & 63, wave = threadIdx.x >> 6;
  const int wm = (wave >> 1) << 6, wn = (wave & 1) << 5;
#pragma unroll
  for (int mi = 0; mi < 4; mi++) {
    const int rbase = row0 + wm + mi * 16 + ((lane >> 4) << 2);
#pragma unroll
    for (int ni = 0; ni < 2; ni++) {
      const int gcol = col0 + wn + ni * 16 + (lane & 15);
      const float bo = b_out[gcol];
#pragma unroll
      for (int reg = 0; reg < 4; reg++) {
        const size_t idx = (size_t)(rbase + reg) * 512 + gcol;
        out[idx] = acc[mi][ni][reg] + bo + x[idx];
      }
    }
  }
}

// ---------------------------------------------------------------------------
// Workspace layout (bytes):
//   h_bf   @ 0          8,388,608   (8192x512 bf16)
//   wqkvT  @ 8388608    6,291,456   (6144x512 bf16, rows (s,h,c)-ordered)
//   woutT  @ 14680064   2,097,152   (512x2048 bf16)
//   q      @ 16777216   33,554,432  (32x512x1024 bf16)   [hv aliases q]
//   k      @ 50331648   33,554,432  (32x512x1024 bf16)
//   vT     @ 83886080   33,554,432  (32x1024x512 bf16)
//   attn   @ 117440512  16,777,216  (32x512x512 bf16)
// ---------------------------------------------------------------------------
extern "C" void kernel_launch(void* const* d_in, const int* in_sizes, int n_in,
                              void* d_out, int out_size, void* d_ws, size_t ws_size,
                              hipStream_t stream) {
  const float* x = (const float*)d_in[0];
  const float* gn_scale = (const float*)d_in[1];
  const float* gn_bias = (const float*)d_in[2];
  const float* w_qkv = (const float*)d_in[3];
  const float* b_qkv = (const float*)d_in[4];
  const float* w_out = (const float*)d_in[5];
  const float* b_out = (const float*)d_in[6];
  float* out = (float*)d_out;

  char* ws = (char*)d_ws;
  unsigned short* h_bf = (unsigned short*)(ws + 0);
  unsigned short* wqkvT = (unsigned short*)(ws + 8388608);
  unsigned short* woutT = (unsigned short*)(ws + 14680064);
  unsigned short* qb = (unsigned short*)(ws + 16777216);
  unsigned short* kb = (unsigned short*)(ws + 50331648);
  unsigned short* vT = (unsigned short*)(ws + 83886080);
  unsigned short* attn = (unsigned short*)(ws + 117440512);
  unsigned short* hv = qb;  // q dead after attn_kernel

  transpose_w_kernel<<<dim3(96, 8), 256, 0, stream>>>(w_qkv, wqkvT, 512, 6144, 1);
  transpose_w_kernel<<<dim3(8, 32), 256, 0, stream>>>(w_out, woutT, 2048, 512, 0);
  groupnorm_kernel<<<256, 256, 0, stream>>>(x, gn_scale, gn_bias, h_bf);
  gemm1_kernel<<<dim3(48, 64), 256, 0, stream>>>(h_bf, wqkvT, b_qkv, qb, kb, vT);
  attn_kernel<<<512, 256, 0, stream>>>(qb, kb, attn);
  gemm3_kernel<<<dim3(8, 4, 32), 256, 0, stream>>>(attn, vT, hv);
  gemm4_kernel<<<dim3(8, 64), 256, 0, stream>>>(hv, woutT, b_out, x, out);
}

// Round 8
// 278.985 us; speedup vs baseline: 1.0734x; 1.0734x over previous
//
#include <hip/hip_runtime.h>
#include <hip/hip_bf16.h>

// AttentionBlock: GroupNorm -> QKV proj -> channel-attention -> out proj -> residual
// B=8, T=1024, C=512, H=4, GROUPS=32, logits scale 1/32.
//
// bf16 MFMA 16x16x32, fp32 accum. 128x128 BK=64 mainloop for gemm1/3/4.
// attn_kernel fuses QK^T/32 + softmax, 64-row strips, BK=64 (z-fastest block
// order keeps all strips of a z on one XCD). Prep (2 weight transposes +
// groupnorm) fused into one dispatch. Staging: global_load_lds width=16 into
// XOR-swizzled stride-32 LDS (0 bank conflicts).

typedef __bf16 bf16x8 __attribute__((ext_vector_type(8)));
typedef float f32x4 __attribute__((ext_vector_type(4)));

__device__ __forceinline__ unsigned short f2bf(float f) {
  union { float f; unsigned u; } x; x.f = f;
  unsigned r = x.u + 0x7fffu + ((x.u >> 16) & 1u);   // RNE
  return (unsigned short)(r >> 16);
}

__device__ __forceinline__ void gload_lds16(const unsigned short* g, unsigned short* l) {
  __builtin_amdgcn_global_load_lds(
      (const __attribute__((address_space(1))) void*)g,
      (__attribute__((address_space(3))) void*)l, 16, 0, 0);
}

// ---------------------------------------------------------------------------
// 128x128 main loop, BK=64: C = A * BT^T; 4 waves each 64x64 (acc 4x4).
// As/Bs each hold two BK=32 sub-tiles at +0/+4096 (32 KB total).
// ---------------------------------------------------------------------------
__device__ __forceinline__ void gemm_mainloop(
    const unsigned short* __restrict__ A, const unsigned short* __restrict__ BT,
    int K, int row0, int col0,
    unsigned short* As, unsigned short* Bs, f32x4 acc[4][4]) {
  const int tid = threadIdx.x;
  const int lane = tid & 63, wave = tid >> 6;
  const int wm = (wave >> 1) << 6, wn = (wave & 1) << 6;
  const int rl = lane & 15;
  const int swz = (((lane >> 4) ^ ((rl >> 1) & 3)) << 3);
  const int srow = tid >> 2;
  const int sg = (((tid & 3) ^ ((tid >> 3) & 3)) << 3);
  const unsigned short* a0 = A + (size_t)(row0 + srow) * K + sg;
  const unsigned short* a1 = A + (size_t)(row0 + 64 + srow) * K + sg;
  const unsigned short* b0 = BT + (size_t)(col0 + srow) * K + sg;
  const unsigned short* b1 = BT + (size_t)(col0 + 64 + srow) * K + sg;
  unsigned short* lA0 = As + tid * 8;
  unsigned short* lA1 = As + 2048 + tid * 8;
  unsigned short* lB0 = Bs + tid * 8;
  unsigned short* lB1 = Bs + 2048 + tid * 8;
#pragma unroll
  for (int mi = 0; mi < 4; mi++)
#pragma unroll
    for (int ni = 0; ni < 4; ni++)
      acc[mi][ni] = (f32x4){0.f, 0.f, 0.f, 0.f};

  for (int k0 = 0; k0 < K; k0 += 64) {
    __syncthreads();
    gload_lds16(a0 + k0, lA0);
    gload_lds16(a1 + k0, lA1);
    gload_lds16(b0 + k0, lB0);
    gload_lds16(b1 + k0, lB1);
    gload_lds16(a0 + k0 + 32, lA0 + 4096);
    gload_lds16(a1 + k0 + 32, lA1 + 4096);
    gload_lds16(b0 + k0 + 32, lB0 + 4096);
    gload_lds16(b1 + k0 + 32, lB1 + 4096);
    __syncthreads();
#pragma unroll
    for (int h = 0; h < 2; h++) {
      const unsigned short* Ah = As + h * 4096;
      const unsigned short* Bh = Bs + h * 4096;
      bf16x8 af[4], bfr[4];
#pragma unroll
      for (int mi = 0; mi < 4; mi++)
        af[mi] = *(const bf16x8*)(Ah + (wm + mi * 16 + rl) * 32 + swz);
#pragma unroll
      for (int ni = 0; ni < 4; ni++)
        bfr[ni] = *(const bf16x8*)(Bh + (wn + ni * 16 + rl) * 32 + swz);
#pragma unroll
      for (int mi = 0; mi < 4; mi++)
#pragma unroll
        for (int ni = 0; ni < 4; ni++)
          acc[mi][ni] = __builtin_amdgcn_mfma_f32_16x16x32_bf16(
              af[mi], bfr[ni], acc[mi][ni], 0, 0, 0);
    }
  }
}

// ---------------------------------------------------------------------------
// Transposed tile store (128x128 accs): dst[(n0+n)*ldd + m_off+m] via LDS.
// ---------------------------------------------------------------------------
__device__ __forceinline__ void epilogue_transpose_store(
    f32x4 acc[4][4], unsigned short* ebuf, unsigned short* dst,
    size_t n0, int ldd, int m_off,
    const float* bias, int bias_base, int bias_stride, int bias_c0) {
  const int tid = threadIdx.x, lane = tid & 63, wave = tid >> 6;
  const int wm = (wave >> 1) << 6;
#pragma unroll
  for (int p = 0; p < 2; p++) {
    __syncthreads();
    if ((wave & 1) == p) {
#pragma unroll
      for (int ni = 0; ni < 4; ni++) {
        const int nl = ni * 16 + (lane & 15);
        const float bq =
            bias ? bias[bias_base + (bias_c0 + p * 64 + nl) * bias_stride] : 0.f;
#pragma unroll
        for (int mi = 0; mi < 4; mi++) {
          const int m = wm + mi * 16 + ((lane >> 4) << 2);
          unsigned short t4[4];
#pragma unroll
          for (int reg = 0; reg < 4; reg++) t4[reg] = f2bf(acc[mi][ni][reg] + bq);
          *(uint2*)(ebuf + nl * 132 + m) = *(const uint2*)t4;
        }
      }
    }
    __syncthreads();
#pragma unroll
    for (int r = 0; r < 2; r++) {
      const int nl = (tid >> 3) + 32 * r;
      const int m = (tid & 7) * 16;
      uint4 v0 = *(const uint4*)(ebuf + nl * 132 + m);
      uint4 v1 = *(const uint4*)(ebuf + nl * 132 + m + 8);
      unsigned short* d = dst + (n0 + p * 64 + nl) * (size_t)ldd + m_off + m;
      *(uint4*)d = v0;
      *(uint4*)(d + 8) = v1;
    }
  }
}

// ---------------------------------------------------------------------------
// Fused prep: blocks [0,768) transpose w_qkv (qkv column reorder);
// [768,1024) transpose w_out; [1024,1280) groupnorm.
// ---------------------------------------------------------------------------
__device__ __forceinline__ void transpose_tile(
    const float* __restrict__ w, unsigned short* __restrict__ wT,
    int R, int N, int mode, int n0, int r0, unsigned short* buf) {
  const int t = threadIdx.x;
  {
    const int rl = t >> 2, nc = (t & 3) * 16;
    const float* src = w + (size_t)(r0 + rl) * N + n0 + nc;
#pragma unroll
    for (int j = 0; j < 16; j++) buf[(nc + j) * 72 + rl] = f2bf(src[j]);
  }
  __syncthreads();
  {
    const int nl = t >> 2, rc = (t & 3) * 16;
    const int n = n0 + nl;
    int p;
    if (mode == 1) {
      const int hh = n / 1536, rem = n - hh * 1536;
      const int c = rem / 3, s = rem - c * 3;
      p = s * 2048 + hh * 512 + c;
    } else {
      p = n;
    }
    unsigned short tmp[16];
#pragma unroll
    for (int j = 0; j < 16; j++) tmp[j] = buf[nl * 72 + rc + j];
    uint4* d = (uint4*)(wT + (size_t)p * R + r0 + rc);
    d[0] = *(const uint4*)tmp;
    d[1] = *(const uint4*)(tmp + 8);
  }
}

__global__ __launch_bounds__(256) void prep_kernel(
    const float* __restrict__ w_qkv, unsigned short* __restrict__ wqkvT,
    const float* __restrict__ w_out, unsigned short* __restrict__ woutT,
    const float* __restrict__ x, const float* __restrict__ scale,
    const float* __restrict__ bias, unsigned short* __restrict__ h) {
  __shared__ unsigned short buf[64 * 72];
  const int bid = blockIdx.x;
  if (bid < 768) {
    transpose_tile(w_qkv, wqkvT, 512, 6144, 1,
                   (bid % 96) * 64, (bid / 96) * 64, buf);
    return;
  }
  if (bid < 1024) {
    const int b2 = bid - 768;
    transpose_tile(w_out, woutT, 2048, 512, 0,
                   (b2 & 7) * 64, (b2 >> 3) * 64, buf);
    return;
  }
  // ---- groupnorm: block b2 = (b, g) ----
  const int b2 = bid - 1024;
  const int b = b2 >> 5, g = b2 & 31;
  const float* xb = x + ((size_t)b * 1024) * 512 + g * 16;
  float* red = (float*)buf;      // 8 floats
  float* stats = red + 8;        // 2 floats
  float s = 0.f, ss = 0.f;
  for (int t = threadIdx.x; t < 1024; t += 256) {
    const float4* p = (const float4*)(xb + (size_t)t * 512);
#pragma unroll
    for (int j = 0; j < 4; j++) {
      float4 u = p[j];
      s += u.x + u.y + u.z + u.w;
      ss += u.x * u.x + u.y * u.y + u.z * u.z + u.w * u.w;
    }
  }
  const int lane = threadIdx.x & 63, wave = threadIdx.x >> 6;
  for (int o = 32; o; o >>= 1) {
    s += __shfl_down(s, o, 64);
    ss += __shfl_down(ss, o, 64);
  }
  if (lane == 0) { red[wave] = s; red[4 + wave] = ss; }
  __syncthreads();
  if (threadIdx.x == 0) {
    float ts = red[0] + red[1] + red[2] + red[3];
    float tss = red[4] + red[5] + red[6] + red[7];
    float mean = ts * (1.f / 16384.f);
    float var = tss * (1.f / 16384.f) - mean * mean;
    stats[0] = mean;
    stats[1] = rsqrtf(var + 1e-5f);
  }
  __syncthreads();
  const float mean = stats[0], inv = stats[1];
  float sc[16], bi[16];
#pragma unroll
  for (int j = 0; j < 16; j++) {
    sc[j] = scale[g * 16 + j] * inv;
    bi[j] = bias[g * 16 + j];
  }
  for (int t = threadIdx.x; t < 1024; t += 256) {
    const float4* p = (const float4*)(xb + (size_t)t * 512);
    unsigned short o16[16];
#pragma unroll
    for (int j = 0; j < 4; j++) {
      float4 u = p[j];
      o16[j * 4 + 0] = f2bf((u.x - mean) * sc[j * 4 + 0] + bi[j * 4 + 0]);
      o16[j * 4 + 1] = f2bf((u.y - mean) * sc[j * 4 + 1] + bi[j * 4 + 1]);
      o16[j * 4 + 2] = f2bf((u.z - mean) * sc[j * 4 + 2] + bi[j * 4 + 2]);
      o16[j * 4 + 3] = f2bf((u.w - mean) * sc[j * 4 + 3] + bi[j * 4 + 3]);
    }
    uint4* dst = (uint4*)(h + ((size_t)(b * 1024 + t)) * 512 + g * 16);
    dst[0] = *(uint4*)(o16);
    dst[1] = *(uint4*)(o16 + 8);
  }
}

// ---------------------------------------------------------------------------
// GEMM1: qkv = h(8192,512) x wqkvT(6144,512)^T (rows (s,h,c)-ordered).
// ---------------------------------------------------------------------------
__global__ __launch_bounds__(256, 3) void gemm1_kernel(
    const unsigned short* __restrict__ h, const unsigned short* __restrict__ wqkvT,
    const float* __restrict__ b_qkv, unsigned short* __restrict__ q,
    unsigned short* __restrict__ k, unsigned short* __restrict__ vT) {
  __shared__ unsigned short smem[16384];
  unsigned short* As = smem;
  unsigned short* Bs = smem + 8192;
  const int row0 = blockIdx.y << 7, col0 = blockIdx.x << 7;
  f32x4 acc[4][4];
  gemm_mainloop(h, wqkvT, 512, row0, col0, As, Bs, acc);

  const int s = col0 >> 11, hh = (col0 >> 9) & 3, c0 = col0 & 511;
  const int b = row0 >> 10, tt0 = row0 & 1023;
  const int bh = b * 4 + hh;
  if (s == 2) {
    const int lane = threadIdx.x & 63, wave = threadIdx.x >> 6;
    const int wm = (wave >> 1) << 6, wn = (wave & 1) << 6;
#pragma unroll
    for (int mi = 0; mi < 4; mi++) {
      const int rbase = tt0 + wm + mi * 16 + ((lane >> 4) << 2);
#pragma unroll
      for (int ni = 0; ni < 4; ni++) {
        const int cc = c0 + wn + ni * 16 + (lane & 15);
        const float bq = b_qkv[hh * 1536 + cc * 3 + 2];
#pragma unroll
        for (int reg = 0; reg < 4; reg++)
          vT[((size_t)(bh * 1024 + rbase + reg)) * 512 + cc] =
              f2bf(acc[mi][ni][reg] + bq);
      }
    }
  } else {
    epilogue_transpose_store(acc, smem, (s == 0) ? q : k,
                             (size_t)bh * 512 + c0, 1024, tt0,
                             b_qkv, hh * 1536 + s, 3, c0);
  }
}

// ---------------------------------------------------------------------------
// Fused attention scores: per block, S[64 c-rows x 512 d-cols] = Q K^T / 32,
// softmax over d, write bf16 attn.  z = blockIdx.x & 31, strip = blockIdx.x>>5
// (z-fastest: all 8 strips of z land on XCD z%8 -> K stays in that L2).
// BK=64: 16 barrier pairs, 64 MFMA/wave each. 4 waves; wave w owns cols
// [w*128, w*128+128): acc[4][8].  LDS: As 8KB + Bs 64KB + reduce 2KB = 74KB.
// ---------------------------------------------------------------------------
__global__ __launch_bounds__(256, 1) void attn_kernel(
    const unsigned short* __restrict__ q, const unsigned short* __restrict__ k,
    unsigned short* __restrict__ attn) {
  __shared__ unsigned short As[64 * 64];
  __shared__ unsigned short Bs[512 * 64];
  __shared__ float red_m[4][64];
  __shared__ float red_s[4][64];
  const int z = blockIdx.x & 31, strip = blockIdx.x >> 5;
  const unsigned short* Q = q + (size_t)z * 512 * 1024 + (size_t)strip * 64 * 1024;
  const unsigned short* K = k + (size_t)z * 512 * 1024;
  unsigned short* P = attn + (size_t)z * 512 * 512 + (size_t)strip * 64 * 512;

  const int tid = threadIdx.x, lane = tid & 63, wave = tid >> 6;
  const int rl = lane & 15, qd = lane >> 4;
  const int swz = ((qd ^ ((rl >> 1) & 3)) << 3);
  const int srow = tid >> 2;
  const int sg = (((tid & 3) ^ ((tid >> 3) & 3)) << 3);
  const unsigned short* qa = Q + (size_t)srow * 1024 + sg;
  const unsigned short* kb = K + (size_t)srow * 1024 + sg;
  unsigned short* lA = As + tid * 8;
  unsigned short* lB = Bs + tid * 8;

  f32x4 acc[4][8];
#pragma unroll
  for (int mi = 0; mi < 4; mi++)
#pragma unroll
    for (int ni = 0; ni < 8; ni++)
      acc[mi][ni] = (f32x4){0.f, 0.f, 0.f, 0.f};

  for (int k0 = 0; k0 < 1024; k0 += 64) {
    __syncthreads();
    gload_lds16(qa + k0, lA);                 // A half0 (64x32)
    gload_lds16(qa + k0 + 32, lA + 2048);     // A half1
#pragma unroll
    for (int c = 0; c < 8; c++) {
      gload_lds16(kb + (size_t)c * 64 * 1024 + k0, lB + c * 2048);
      gload_lds16(kb + (size_t)c * 64 * 1024 + k0 + 32, lB + 16384 + c * 2048);
    }
    __syncthreads();
#pragma unroll
    for (int h = 0; h < 2; h++) {
      const unsigned short* Ah = As + h * 2048;
      const unsigned short* Bh = Bs + h * 16384;
      bf16x8 af[4], bfr[8];
#pragma unroll
      for (int mi = 0; mi < 4; mi++)
        af[mi] = *(const bf16x8*)(Ah + (mi * 16 + rl) * 32 + swz);
#pragma unroll
      for (int ni = 0; ni < 8; ni++) {
        const int chunk = wave * 2 + (ni >> 2);
        bfr[ni] = *(const bf16x8*)(Bh + chunk * 2048 + ((ni & 3) * 16 + rl) * 32 + swz);
      }
#pragma unroll
      for (int mi = 0; mi < 4; mi++)
#pragma unroll
        for (int ni = 0; ni < 8; ni++)
          acc[mi][ni] = __builtin_amdgcn_mfma_f32_16x16x32_bf16(
              af[mi], bfr[ni], acc[mi][ni], 0, 0, 0);
    }
  }

  // ---- softmax over the 512 cols (raw logits; scale folded into exp) ----
  float pm[4][4];
#pragma unroll
  for (int mi = 0; mi < 4; mi++)
#pragma unroll
    for (int reg = 0; reg < 4; reg++) {
      float m = acc[mi][0][reg];
#pragma unroll
      for (int ni = 1; ni < 8; ni++) m = fmaxf(m, acc[mi][ni][reg]);
      pm[mi][reg] = m;
    }
#pragma unroll
  for (int o = 1; o < 16; o <<= 1)
#pragma unroll
    for (int mi = 0; mi < 4; mi++)
#pragma unroll
      for (int reg = 0; reg < 4; reg++)
        pm[mi][reg] = fmaxf(pm[mi][reg], __shfl_xor(pm[mi][reg], o, 64));
  if (rl == 0)
#pragma unroll
    for (int mi = 0; mi < 4; mi++)
#pragma unroll
      for (int reg = 0; reg < 4; reg++)
        red_m[wave][mi * 16 + qd * 4 + reg] = pm[mi][reg];
  __syncthreads();
  float mf[4][4], ps[4][4];
#pragma unroll
  for (int mi = 0; mi < 4; mi++)
#pragma unroll
    for (int reg = 0; reg < 4; reg++) {
      const int row = mi * 16 + qd * 4 + reg;
      mf[mi][reg] = fmaxf(fmaxf(red_m[0][row], red_m[1][row]),
                          fmaxf(red_m[2][row], red_m[3][row]));
      ps[mi][reg] = 0.f;
    }
#pragma unroll
  for (int mi = 0; mi < 4; mi++)
#pragma unroll
    for (int ni = 0; ni < 8; ni++)
#pragma unroll
      for (int reg = 0; reg < 4; reg++) {
        const float e = __expf((acc[mi][ni][reg] - mf[mi][reg]) * 0.03125f);
        acc[mi][ni][reg] = e;
        ps[mi][reg] += e;
      }
#pragma unroll
  for (int o = 1; o < 16; o <<= 1)
#pragma unroll
    for (int mi = 0; mi < 4; mi++)
#pragma unroll
      for (int reg = 0; reg < 4; reg++)
        ps[mi][reg] += __shfl_xor(ps[mi][reg], o, 64);
  if (rl == 0)
#pragma unroll
    for (int mi = 0; mi < 4; mi++)
#pragma unroll
      for (int reg = 0; reg < 4; reg++)
        red_s[wave][mi * 16 + qd * 4 + reg] = ps[mi][reg];
  __syncthreads();
#pragma unroll
  for (int mi = 0; mi < 4; mi++)
#pragma unroll
    for (int reg = 0; reg < 4; reg++) {
      const int row = mi * 16 + qd * 4 + reg;
      const float inv = 1.f / (red_s[0][row] + red_s[1][row] +
                               red_s[2][row] + red_s[3][row]);
      unsigned short* pr = P + (size_t)row * 512 + wave * 128 + rl;
#pragma unroll
      for (int ni = 0; ni < 8; ni++)
        pr[ni * 16] = f2bf(acc[mi][ni][reg] * inv);
    }
}

// ---------------------------------------------------------------------------
// GEMM3: av[z](c,t) = attn[z](512,512) x vT[z](1024,512)^T -> hv (b,t,h*512+c).
// Grid (32,8,4), z = blockIdx.x (z-first: z's 2MB working set stays on XCD z%8).
// ---------------------------------------------------------------------------
__global__ __launch_bounds__(256, 3) void gemm3_kernel(
    const unsigned short* __restrict__ attn, const unsigned short* __restrict__ vT,
    unsigned short* __restrict__ hv) {
  __shared__ unsigned short smem[16384];
  unsigned short* As = smem;
  unsigned short* Bs = smem + 8192;
  const int z = blockIdx.x;
  const int bb = z >> 2, hh = z & 3;
  const unsigned short* A = attn + (size_t)z * 512 * 512;
  const unsigned short* BT = vT + (size_t)z * 1024 * 512;
  const int row0 = blockIdx.z << 7, col0 = blockIdx.y << 7;
  f32x4 acc[4][4];
  gemm_mainloop(A, BT, 512, row0, col0, As, Bs, acc);
  epilogue_transpose_store(acc, smem, hv,
                           (size_t)bb * 1024 + col0, 2048, hh * 512 + row0,
                           nullptr, 0, 0, 0);
}

// ---------------------------------------------------------------------------
// GEMM4: out = hv(8192,2048) x woutT(512,2048)^T + b_out + x, fp32.
// 128x128 tiles, BK=64.
// ---------------------------------------------------------------------------
__global__ __launch_bounds__(256, 3) void gemm4_kernel(
    const unsigned short* __restrict__ hv, const unsigned short* __restrict__ woutT,
    const float* __restrict__ b_out, const float* __restrict__ x,
    float* __restrict__ out) {
  __shared__ unsigned short smem[16384];
  unsigned short* As = smem;
  unsigned short* Bs = smem + 8192;
  const int row0 = blockIdx.y << 7, col0 = blockIdx.x << 7;
  f32x4 acc[4][4];
  gemm_mainloop(hv, woutT, 2048, row0, col0, As, Bs, acc);
  const int lane = threadIdx.x & 63, wave = threadIdx.x >> 6;
  const int wm = (wave >> 1) << 6, wn = (wave & 1) << 6;
#pragma unroll
  for (int mi = 0; mi < 4; mi++) {
    const int rbase = row0 + wm + mi * 16 + ((lane >> 4) << 2);
#pragma unroll
    for (int ni = 0; ni < 4; ni++) {
      const int gcol = col0 + wn + ni * 16 + (lane & 15);
      const float bo = b_out[gcol];
#pragma unroll
      for (int reg = 0; reg < 4; reg++) {
        const size_t idx = (size_t)(rbase + reg) * 512 + gcol;
        out[idx] = acc[mi][ni][reg] + bo + x[idx];
      }
    }
  }
}

// ---------------------------------------------------------------------------
// Workspace layout (bytes):
//   h_bf   @ 0          8,388,608   (8192x512 bf16)
//   wqkvT  @ 8388608    6,291,456   (6144x512 bf16, rows (s,h,c)-ordered)
//   woutT  @ 14680064   2,097,152   (512x2048 bf16)
//   q      @ 16777216   33,554,432  (32x512x1024 bf16)   [hv aliases q]
//   k      @ 50331648   33,554,432  (32x512x1024 bf16)
//   vT     @ 83886080   33,554,432  (32x1024x512 bf16)
//   attn   @ 117440512  16,777,216  (32x512x512 bf16)
// ---------------------------------------------------------------------------
extern "C" void kernel_launch(void* const* d_in, const int* in_sizes, int n_in,
                              void* d_out, int out_size, void* d_ws, size_t ws_size,
                              hipStream_t stream) {
  const float* x = (const float*)d_in[0];
  const float* gn_scale = (const float*)d_in[1];
  const float* gn_bias = (const float*)d_in[2];
  const float* w_qkv = (const float*)d_in[3];
  const float* b_qkv = (const float*)d_in[4];
  const float* w_out = (const float*)d_in[5];
  const float* b_out = (const float*)d_in[6];
  float* out = (float*)d_out;

  char* ws = (char*)d_ws;
  unsigned short* h_bf = (unsigned short*)(ws + 0);
  unsigned short* wqkvT = (unsigned short*)(ws + 8388608);
  unsigned short* woutT = (unsigned short*)(ws + 14680064);
  unsigned short* qb = (unsigned short*)(ws + 16777216);
  unsigned short* kb = (unsigned short*)(ws + 50331648);
  unsigned short* vT = (unsigned short*)(ws + 83886080);
  unsigned short* attn = (unsigned short*)(ws + 117440512);
  unsigned short* hv = qb;  // q dead after attn_kernel

  prep_kernel<<<1280, 256, 0, stream>>>(w_qkv, wqkvT, w_out, woutT,
                                        x, gn_scale, gn_bias, h_bf);
  gemm1_kernel<<<dim3(48, 64), 256, 0, stream>>>(h_bf, wqkvT, b_qkv, qb, kb, vT);
  attn_kernel<<<256, 256, 0, stream>>>(qb, kb, attn);
  gemm3_kernel<<<dim3(32, 8, 4), 256, 0, stream>>>(attn, vT, hv);
  gemm4_kernel<<<dim3(4, 64), 256, 0, stream>>>(hv, woutT, b_out, x, out);
}